// Round 1
// baseline (701.045 us; speedup 1.0000x reference)
//
#include <hip/hip_runtime.h>

#define LSEQ 2048
#define NH   16
#define HD   64

typedef __attribute__((ext_vector_type(8))) short short8;
typedef __attribute__((ext_vector_type(4))) float f32x4;

__device__ __forceinline__ unsigned short f2b(float x) {
  unsigned int u = __builtin_bit_cast(unsigned int, x);
  u += 0x7FFFu + ((u >> 16) & 1u);   // round-to-nearest-even to bf16
  return (unsigned short)(u >> 16);
}

// Prep: q*0.125 -> bf16 [b][l][d]; k -> bf16 [b][l][d]; v -> bf16 TRANSPOSED [b][d][l]
__global__ __launch_bounds__(256) void prep_kernel(
    const float* __restrict__ q, const float* __restrict__ k, const float* __restrict__ v,
    unsigned short* __restrict__ qb, unsigned short* __restrict__ kb,
    unsigned short* __restrict__ vt) {
  const int b = blockIdx.y, lt = blockIdx.x;
  const int t = threadIdx.x;
  __shared__ float vlds[64][65];
  const int l0 = lt * 64;
  #pragma unroll
  for (int i = 0; i < 4; ++i) {
    int r = (t >> 4) + 16 * i;
    size_t base = ((size_t)(b * LSEQ + l0 + r)) * HD + (t & 15) * 4;
    float4 qv = *(const float4*)(q + base);
    float4 kv = *(const float4*)(k + base);
    float4 vv = *(const float4*)(v + base);
    ushort4 qo, ko;
    qo.x = f2b(qv.x * 0.125f); qo.y = f2b(qv.y * 0.125f);
    qo.z = f2b(qv.z * 0.125f); qo.w = f2b(qv.w * 0.125f);
    ko.x = f2b(kv.x); ko.y = f2b(kv.y); ko.z = f2b(kv.z); ko.w = f2b(kv.w);
    *(ushort4*)(qb + base) = qo;
    *(ushort4*)(kb + base) = ko;
    int c = (t & 15) * 4;
    vlds[r][c] = vv.x; vlds[r][c + 1] = vv.y; vlds[r][c + 2] = vv.z; vlds[r][c + 3] = vv.w;
  }
  __syncthreads();
  const int ll = t & 63;
  const int dbase = (t >> 6) * 16;
  #pragma unroll
  for (int i = 0; i < 16; ++i) {
    int d = dbase + i;
    vt[((size_t)(b * HD + d)) * LSEQ + l0 + ll] = f2b(vlds[ll][d]);
  }
}

// Main: per block = (head b, 64 Q rows). 4 waves x 16 rows. Two K passes:
// pass 1 accumulates l = sum exp(s); pass 2 recomputes S, writes attn/log_attn,
// and accumulates O += P@V via MFMA (P round-trips through per-wave LDS for
// the C-layout -> A-layout transform).
__global__ __launch_bounds__(256) void attn_kernel(
    const unsigned short* __restrict__ qb, const unsigned short* __restrict__ kb,
    const unsigned short* __restrict__ vt,
    float* __restrict__ out0, float* __restrict__ attn, float* __restrict__ logp) {
  const int b = blockIdx.y, qt = blockIdx.x;
  const int t = threadIdx.x;
  const int w = t >> 6, lane = t & 63, quad = lane >> 4, l16 = lane & 15;
  __shared__ unsigned short ps[4][16][72];   // per-wave P strip, padded stride

  const int q0 = qt * 64;
  const int qrl = quad * 4;  // + r gives local q row of this lane's C regs

  // Q A-frags: A[m=l16][k=quad*8+j], k = d (two ksteps of 32). Loaded once.
  const unsigned short* qrow = qb + ((size_t)(b * LSEQ + q0 + w * 16 + l16)) * HD;
  short8 aq0 = *(const short8*)(qrow + quad * 8);
  short8 aq1 = *(const short8*)(qrow + 32 + quad * 8);

  // ---- pass 1: l = sum_k exp(s) (no max subtraction; |s| <= ~6, safe in fp32)
  float p0 = 0.f, p1 = 0.f, p2 = 0.f, p3 = 0.f;
  for (int kt = 0; kt < 32; ++kt) {
    const unsigned short* kbase = kb + ((size_t)(b * LSEQ + kt * 64)) * HD;
    #pragma unroll
    for (int nt = 0; nt < 4; ++nt) {
      const unsigned short* krow = kbase + (nt * 16 + l16) * HD + quad * 8;
      short8 b0 = *(const short8*)(krow);
      short8 b1 = *(const short8*)(krow + 32);
      f32x4 s = {0.f, 0.f, 0.f, 0.f};
      s = __builtin_amdgcn_mfma_f32_16x16x32_bf16(aq0, b0, s, 0, 0, 0);
      s = __builtin_amdgcn_mfma_f32_16x16x32_bf16(aq1, b1, s, 0, 0, 0);
      p0 += __expf(s[0]); p1 += __expf(s[1]);
      p2 += __expf(s[2]); p3 += __expf(s[3]);
    }
  }
  #pragma unroll
  for (int off = 1; off < 16; off <<= 1) {
    p0 += __shfl_xor(p0, off, 64);
    p1 += __shfl_xor(p1, off, 64);
    p2 += __shfl_xor(p2, off, 64);
    p3 += __shfl_xor(p3, off, 64);
  }
  const float logl0 = __logf(p0), logl1 = __logf(p1);
  const float logl2 = __logf(p2), logl3 = __logf(p3);

  // ---- pass 2: recompute S, emit attn/log_attn, accumulate O = P@V
  f32x4 oacc[4] = {{0.f,0.f,0.f,0.f},{0.f,0.f,0.f,0.f},{0.f,0.f,0.f,0.f},{0.f,0.f,0.f,0.f}};
  const size_t arow0 = ((size_t)(b * LSEQ + q0 + w * 16 + qrl)) * LSEQ;

  for (int kt = 0; kt < 32; ++kt) {
    const unsigned short* kbase = kb + ((size_t)(b * LSEQ + kt * 64)) * HD;
    #pragma unroll
    for (int nt = 0; nt < 4; ++nt) {
      const unsigned short* krow = kbase + (nt * 16 + l16) * HD + quad * 8;
      short8 b0 = *(const short8*)(krow);
      short8 b1 = *(const short8*)(krow + 32);
      f32x4 s = {0.f, 0.f, 0.f, 0.f};
      s = __builtin_amdgcn_mfma_f32_16x16x32_bf16(aq0, b0, s, 0, 0, 0);
      s = __builtin_amdgcn_mfma_f32_16x16x32_bf16(aq1, b1, s, 0, 0, 0);
      const int col = kt * 64 + nt * 16 + l16;
      const float la0 = s[0] - logl0; const float a0 = __expf(la0);
      const float la1 = s[1] - logl1; const float a1 = __expf(la1);
      const float la2 = s[2] - logl2; const float a2 = __expf(la2);
      const float la3 = s[3] - logl3; const float a3 = __expf(la3);
      attn[arow0 + col]            = a0;  logp[arow0 + col]            = la0;
      attn[arow0 + LSEQ + col]     = a1;  logp[arow0 + LSEQ + col]     = la1;
      attn[arow0 + 2 * LSEQ + col] = a2;  logp[arow0 + 2 * LSEQ + col] = la2;
      attn[arow0 + 3 * LSEQ + col] = a3;  logp[arow0 + 3 * LSEQ + col] = la3;
      ps[w][qrl + 0][nt * 16 + l16] = f2b(a0);
      ps[w][qrl + 1][nt * 16 + l16] = f2b(a1);
      ps[w][qrl + 2][nt * 16 + l16] = f2b(a2);
      ps[w][qrl + 3][nt * 16 + l16] = f2b(a3);
    }
    // per-wave LDS buffer: only need in-wave ordering, no barrier
    asm volatile("s_waitcnt lgkmcnt(0)" ::: "memory");
    short8 ap0 = *(const short8*)(&ps[w][l16][quad * 8]);
    short8 ap1 = *(const short8*)(&ps[w][l16][32 + quad * 8]);
    #pragma unroll
    for (int nt = 0; nt < 4; ++nt) {
      const unsigned short* vrow =
          vt + ((size_t)(b * HD + nt * 16 + l16)) * LSEQ + kt * 64 + quad * 8;
      short8 v0 = *(const short8*)(vrow);
      short8 v1 = *(const short8*)(vrow + 32);
      oacc[nt] = __builtin_amdgcn_mfma_f32_16x16x32_bf16(ap0, v0, oacc[nt], 0, 0, 0);
      oacc[nt] = __builtin_amdgcn_mfma_f32_16x16x32_bf16(ap1, v1, oacc[nt], 0, 0, 0);
    }
    // reads of ps must retire before next iteration overwrites it
    asm volatile("s_waitcnt lgkmcnt(0)" ::: "memory");
  }

  // out[l, b*64+d] = O[q][d]
  #pragma unroll
  for (int nt = 0; nt < 4; ++nt) {
    #pragma unroll
    for (int r = 0; r < 4; ++r) {
      out0[((size_t)(q0 + w * 16 + qrl + r)) * (NH * HD) + b * HD + nt * 16 + l16] =
          oacc[nt][r];
    }
  }
}

extern "C" void kernel_launch(void* const* d_in, const int* in_sizes, int n_in,
                              void* d_out, int out_size, void* d_ws, size_t ws_size,
                              hipStream_t stream) {
  const float* q = (const float*)d_in[0];
  const float* k = (const float*)d_in[1];
  const float* v = (const float*)d_in[2];
  float* out0 = (float*)d_out;
  float* attn = out0 + (size_t)LSEQ * NH * HD;            // 2,097,152
  float* logp = attn + (size_t)NH * LSEQ * LSEQ;          // +67,108,864

  unsigned short* qb = (unsigned short*)d_ws;             // 4 MB
  unsigned short* kb = qb + (size_t)NH * LSEQ * HD;       // 4 MB
  unsigned short* vt = kb + (size_t)NH * LSEQ * HD;       // 4 MB (transposed V)

  dim3 grid(LSEQ / 64, NH);
  prep_kernel<<<grid, 256, 0, stream>>>(q, k, v, qb, kb, vt);
  attn_kernel<<<grid, 256, 0, stream>>>(qb, kb, vt, out0, attn, logp);
}